// Round 16
// baseline (299.727 us; speedup 1.0000x reference)
//
#include <hip/hip_runtime.h>
#include <hip/hip_bf16.h>
#include <math.h>

#define BB 16
#define TT 256
#define CC 256
#define INNER 64
#define TPR 10
#define THD 32
#define EPSV 1e-5f

typedef __attribute__((ext_vector_type(8))) short short8;
typedef __attribute__((ext_vector_type(4))) float f32x4;
typedef __attribute__((ext_vector_type(4))) unsigned int u32x4;

__device__ __forceinline__ short f2bf(float f) {
    unsigned u = __float_as_uint(f);
    u += 0x7fffu + ((u >> 16) & 1);   // RNE
    return (short)(u >> 16);
}
__device__ __forceinline__ unsigned cvtpk(float a, float b) {
    __hip_bfloat162 h = __float22bfloat162_rn(float2{a, b});
    return *(unsigned*)&h;
}

// ---- weight image (in ws): WT1/c1 linear (read direct); WT2/WA1/WA2 PRE-SWIZZLED for LDS ----
#define IMG_WT1  0        // [32 m][32 k] bf16 linear (k>=10 zero)    2KB
#define IMG_WT2  2048     // [c>>1][128B] paired rows, mask-7 swizzle 4KB
#define IMG_WA1  6144     // [64 c][128B] mask-7 swizzle              8KB
#define IMG_WA2  14336    // [64 c][128B] mask-7 swizzle              8KB
#define IMG_C1   22528    // f32[32] folded BN bias                   128B
#define IMG_SZ   22656

__device__ __forceinline__ int sww(int pb, int key) {
    return ((pb & ~15) ^ key) | (pb & 15);
}

// ---------------- prep: bf16 weight images + folded BN ----------------
__global__ __launch_bounds__(256) void prep_kernel(
    const float* __restrict__ Wt1, const float* __restrict__ bt1,
    const float* __restrict__ gt, const float* __restrict__ bbt,
    const float* __restrict__ mt, const float* __restrict__ vt,
    const float* __restrict__ Wt2, const float* __restrict__ Wa1,
    const float* __restrict__ Wa2, char* __restrict__ img)
{
    const int blk = blockIdx.x, t = threadIdx.x;
    if (blk == 0) {
        for (int e = t; e < 32 * 32; e += 256) {
            int m = e >> 5, k = e & 31;
            float scv = gt[m] * rsqrtf(vt[m] + EPSV);
            float v = (k < TPR) ? Wt1[k * 32 + m] * scv : 0.f;
            *(short*)(img + IMG_WT1 + m * 64 + k * 2) = f2bf(v);
        }
        if (t < 32) {
            float scv = gt[t] * rsqrtf(vt[t] + EPSV);
            ((float*)(img + IMG_C1))[t] = (bt1[t] - mt[t]) * scv + bbt[t];
        }
    } else if (blk == 1) {
        for (int e = t; e < 32 * 64; e += 256) {
            int h = e >> 6, c = e & 63;
            int off = IMG_WT2 + (c >> 1) * 128 + sww((c & 1) * 64 + h * 2, ((c >> 1) & 7) << 4);
            *(short*)(img + off) = f2bf(Wt2[e]);
        }
    } else {
        const float* W = (blk == 2) ? Wa1 : Wa2;
        int base = (blk == 2) ? IMG_WA1 : IMG_WA2;
        for (int e = t; e < 64 * 64; e += 256) {
            int k = e >> 6, c = e & 63;
            int off = base + c * 128 + sww(k * 2, (c & 7) << 4);
            *(short*)(img + off) = f2bf(W[e]);
        }
    }
}

// ---------------- Kernel A: y = BN(x@W1+b1); skip=y; qkv = relu(y)@Wqkv ----------------
__global__ __launch_bounds__(256) void fc1_qkv_kernel(
    const float* __restrict__ x, const float* __restrict__ W1, const float* __restrict__ b1,
    const float* __restrict__ g1, const float* __restrict__ bb1,
    const float* __restrict__ m1, const float* __restrict__ v1,
    const float* __restrict__ Wqkv,
    float* __restrict__ skip, float* __restrict__ qkv)
{
    const int ROWS = 8;
    __shared__ float xr[ROWS][CC];
    __shared__ float yr[ROWS][CC];
    const int n0 = blockIdx.x * ROWS;
    const int t = threadIdx.x;

#pragma unroll
    for (int rr = 0; rr < ROWS; ++rr)
        xr[rr][t] = x[(size_t)(n0 + rr) * CC + t];
    __syncthreads();

    float acc[ROWS];
#pragma unroll
    for (int rr = 0; rr < ROWS; ++rr) acc[rr] = 0.f;
    for (int k = 0; k < CC; ++k) {
        float wv = W1[(size_t)k * CC + t];
#pragma unroll
        for (int rr = 0; rr < ROWS; ++rr) acc[rr] = fmaf(xr[rr][k], wv, acc[rr]);
    }
    const float s1 = g1[t] * rsqrtf(v1[t] + EPSV);
    const float base = b1[t] - m1[t];
    const float bet = bb1[t];
#pragma unroll
    for (int rr = 0; rr < ROWS; ++rr) {
        float y = (acc[rr] + base) * s1 + bet;
        skip[(size_t)(n0 + rr) * CC + t] = y;
        yr[rr][t] = fmaxf(y, 0.f);
    }
    __syncthreads();

    if (t < 192) {
        float a2[ROWS];
#pragma unroll
        for (int rr = 0; rr < ROWS; ++rr) a2[rr] = 0.f;
        for (int k = 0; k < CC; ++k) {
            float wv = Wqkv[(size_t)k * 192 + t];
#pragma unroll
            for (int rr = 0; rr < ROWS; ++rr) a2[rr] = fmaf(yr[rr][k], wv, a2[rr]);
        }
#pragma unroll
        for (int rr = 0; rr < ROWS; ++rr)
            qkv[(size_t)(n0 + rr) * 192 + t] = a2[rr];
    }
}

// ---------------- Kernel B: MFMA fused vector-attention ----------------
// block = 256 (4 waves) = one (b,i); `#pragma unroll 1` loop over 4 j-quarters;
// each wave owns 16 j-rows per quarter (R13's proven 52-reg shape, tn=1).
// WT2/WA1/WA2 LDS-resident (pre-swizzled, staged once via global_load_lds);
// WT1/c1 direct from global (L2-hot). Softmax partials accumulate in RED.
#define O_WT2  0        // 4KB  paired rows mask-7
#define O_WA1  4096     // 8KB
#define O_WA2  12288    // 8KB
#define O_TH   20480    // [64 rows][128B] mask-7: hid -> t -> h2 (wave-local rows)
#define O_RED  28672    // 4 waves x 4 tm x 4 q4 x 32B = 2KB
#define LDSZ   30720

__device__ __forceinline__ int swb(int row, int cb) {
    return (row << 7) + (((cb & ~15) ^ ((row & 7) << 4)) | (cb & 15));
}
__device__ __forceinline__ short8 ldfrag(const char* lds, int base, int row, int cb16) {
    return *(const short8*)(lds + base + (row << 7) + (cb16 ^ ((row & 7) << 4)));
}
__device__ __forceinline__ short8 ldTH(const char* lds, int row, int cb16) {
    return *(const short8*)(lds + O_TH + (row << 7) + (cb16 ^ ((row & 7) << 4)));
}

__global__ __launch_bounds__(256, 4) void attn_mfma_kernel(
    const float* __restrict__ r, const float* __restrict__ qkv,
    const float* __restrict__ bt2, const float* __restrict__ ba1,
    const char* __restrict__ img, float* __restrict__ agg)
{
    __shared__ __align__(16) char lds[LDSZ];
    const int n = blockIdx.x, b = n >> 8;
    const int tid = threadIdx.x;
    const int wv = tid >> 6, lane = tid & 63;
    const int lid = lane & 15, q4 = lane >> 4;
    const int kb = q4 * 16;
    const int jloc = wv * 16 + lid;    // this thread's TH row (0..63)

    const float* kvb = qkv + (size_t)b * (TT * 192);
    const f32x4 z4 = {0.f, 0.f, 0.f, 0.f};

    // ---- stage WT2/WA1/WA2 (20 x 1KB, pre-swizzled image -> linear LDS copy)
#pragma unroll
    for (int ci = 0; ci < 5; ++ci) {
        int c = wv + ci * 4;
        int ldsoff = (c < 4) ? O_WT2 + c * 1024
                   : (c < 12) ? O_WA1 + (c - 4) * 1024
                              : O_WA2 + (c - 12) * 1024;
        __builtin_amdgcn_global_load_lds(
            (const __attribute__((address_space(1))) unsigned*)(const unsigned*)(img + IMG_WT2 + c * 1024 + lane * 16),
            (__attribute__((address_space(3))) unsigned*)(unsigned*)(lds + ldsoff + lane * 16),
            16, 0, 0);
    }

    // ---- cb = bt2 + q (uniform over j -> GEMM2 C-operand)
    f32x4 cbv[4];
#pragma unroll
    for (int tm = 0; tm < 4; ++tm) {
        int ch0 = tm * 16 + q4 * 4;
        f32x4 qv = *(const f32x4*)(qkv + (size_t)n * 192 + ch0);
        f32x4 bv = *(const f32x4*)(bt2 + ch0);
#pragma unroll
        for (int g = 0; g < 4; ++g) cbv[tm][g] = qv[g] + bv[g];
    }

    // ---- GEMM1 A-fragments + c1 from global img (L2-hot; held across quarters)
    const short8 a10 = *(const short8*)(img + IMG_WT1 + lid * 64 + kb);
    const short8 a11 = *(const short8*)(img + IMG_WT1 + (16 + lid) * 64 + kb);
    const float* c1g = (const float*)(img + IMG_C1);
    const f32x4 c1v0 = *(const f32x4*)(c1g + q4 * 4);
    const f32x4 c1v1 = *(const f32x4*)(c1g + 16 + q4 * 4);

    __syncthreads();

#pragma unroll 1
    for (int qq = 0; qq < 4; ++qq) {
        const int jglob = qq * 64 + jloc;   // this thread's global j row

        // ---- GEMM1: hid = relu(Wt1f^T @ r^T + c1); B built direct from r (cold HBM)
        {
            const float* rj = r + (size_t)n * (TT * TPR) + (size_t)jglob * TPR;
            union { short8 s8; u32x4 u; } bbf;
            bbf.u[0] = 0u; bbf.u[1] = 0u; bbf.u[2] = 0u; bbf.u[3] = 0u;
            if (q4 == 0) {
                float2 a0 = *(const float2*)(rj);
                float2 a1 = *(const float2*)(rj + 2);
                float2 a2 = *(const float2*)(rj + 4);
                float2 a3 = *(const float2*)(rj + 6);
                bbf.u[0] = cvtpk(a0.x, a0.y); bbf.u[1] = cvtpk(a1.x, a1.y);
                bbf.u[2] = cvtpk(a2.x, a2.y); bbf.u[3] = cvtpk(a3.x, a3.y);
            } else if (q4 == 1) {
                float2 a0 = *(const float2*)(rj + 8);
                bbf.u[0] = cvtpk(a0.x, a0.y);
            }
            f32x4 acc1[2];
            acc1[0] = __builtin_amdgcn_mfma_f32_16x16x32_bf16(a10, bbf.s8, c1v0, 0, 0, 0);
            acc1[1] = __builtin_amdgcn_mfma_f32_16x16x32_bf16(a11, bbf.s8, c1v1, 0, 0, 0);
#pragma unroll
            for (int tm = 0; tm < 2; ++tm) {
                uint2 w;
                w.x = cvtpk(fmaxf(acc1[tm][0], 0.f), fmaxf(acc1[tm][1], 0.f));
                w.y = cvtpk(fmaxf(acc1[tm][2], 0.f), fmaxf(acc1[tm][3], 0.f));
                *(uint2*)(lds + O_TH + swb(jloc, tm * 32 + q4 * 8)) = w;
            }
        }

        // ---- GEMM2: R1 = Wt2^T @ hid^T + (bt2+q); t = R1 - k -> TH; vvp = bf16(v + R1 - cb)
        uint2 vvp[4];
        {
            short8 bfh = ldTH(lds, jloc, kb);
#pragma unroll
            for (int tm = 0; tm < 4; ++tm) {
                int c = tm * 16 + lid;
                short8 aw = ldfrag(lds, O_WT2, c >> 1, (c & 1) * 64 + kb);
                f32x4 kx = *(const f32x4*)(kvb + (size_t)jglob * 192 + 64 + tm * 16 + q4 * 4);
                f32x4 vx = *(const f32x4*)(kvb + (size_t)jglob * 192 + 128 + tm * 16 + q4 * 4);
                f32x4 rr = __builtin_amdgcn_mfma_f32_16x16x32_bf16(aw, bfh, cbv[tm], 0, 0, 0);
                uint2 w;
                w.x = cvtpk(rr[0] - kx[0], rr[1] - kx[1]);
                w.y = cvtpk(rr[2] - kx[2], rr[3] - kx[3]);
                *(uint2*)(lds + O_TH + swb(jloc, tm * 32 + q4 * 8)) = w;
                vvp[tm].x = cvtpk(vx[0] + rr[0] - cbv[tm][0], vx[1] + rr[1] - cbv[tm][1]);
                vvp[tm].y = cvtpk(vx[2] + rr[2] - cbv[tm][2], vx[3] + rr[3] - cbv[tm][3]);
            }
        }

        // ---- GEMM3: h2 = relu(Wa1^T @ t^T + ba1)
        f32x4 acc[4];
#pragma unroll
        for (int tm = 0; tm < 4; ++tm)
            acc[tm] = *(const f32x4*)(ba1 + tm * 16 + q4 * 4);
#pragma unroll
        for (int ks = 0; ks < 2; ++ks) {
            short8 bt = ldTH(lds, jloc, ks * 64 + kb);
#pragma unroll
            for (int tm = 0; tm < 4; ++tm) {
                short8 aw = ldfrag(lds, O_WA1, tm * 16 + lid, ks * 64 + kb);
                acc[tm] = __builtin_amdgcn_mfma_f32_16x16x32_bf16(aw, bt, acc[tm], 0, 0, 0);
            }
        }
#pragma unroll
        for (int tm = 0; tm < 4; ++tm) {
            uint2 w;
            w.x = cvtpk(fmaxf(acc[tm][0], 0.f), fmaxf(acc[tm][1], 0.f));
            w.y = cvtpk(fmaxf(acc[tm][2], 0.f), fmaxf(acc[tm][3], 0.f));
            *(uint2*)(lds + O_TH + swb(jloc, tm * 32 + q4 * 8)) = w;
        }

        // ---- GEMM4: sim = Wa2^T @ h2^T (ba2 cancels in softmax)
#pragma unroll
        for (int tm = 0; tm < 4; ++tm) acc[tm] = z4;
#pragma unroll
        for (int ks = 0; ks < 2; ++ks) {
            short8 bt = ldTH(lds, jloc, ks * 64 + kb);
#pragma unroll
            for (int tm = 0; tm < 4; ++tm) {
                short8 aw = ldfrag(lds, O_WA2, tm * 16 + lid, ks * 64 + kb);
                acc[tm] = __builtin_amdgcn_mfma_f32_16x16x32_bf16(aw, bt, acc[tm], 0, 0, 0);
            }
        }

        // ---- partial softmax sums over this wave's 16 j; accumulate into RED
#pragma unroll
        for (int tm = 0; tm < 4; ++tm) {
            f32x4 num, den;
            float vf0 = __uint_as_float(vvp[tm].x << 16);
            float vf1 = __uint_as_float(vvp[tm].x & 0xffff0000u);
            float vf2 = __uint_as_float(vvp[tm].y << 16);
            float vf3 = __uint_as_float(vvp[tm].y & 0xffff0000u);
            den[0] = __expf(acc[tm][0]); num[0] = den[0] * vf0;
            den[1] = __expf(acc[tm][1]); num[1] = den[1] * vf1;
            den[2] = __expf(acc[tm][2]); num[2] = den[2] * vf2;
            den[3] = __expf(acc[tm][3]); num[3] = den[3] * vf3;
#pragma unroll
            for (int ofs = 1; ofs < 16; ofs <<= 1) {
#pragma unroll
                for (int g = 0; g < 4; ++g) {
                    num[g] += __shfl_xor(num[g], ofs);
                    den[g] += __shfl_xor(den[g], ofs);
                }
            }
            if (lid == 0) {
                float* pb = (float*)(lds + O_RED + ((wv * 4 + tm) * 4 + q4) * 32);
                if (qq == 0) {
                    *(f32x4*)(pb) = num;
                    *(f32x4*)(pb + 4) = den;
                } else {
                    f32x4 on = *(f32x4*)(pb), od = *(f32x4*)(pb + 4);
#pragma unroll
                    for (int g = 0; g < 4; ++g) { on[g] += num[g]; od[g] += den[g]; }
                    *(f32x4*)(pb) = on;
                    *(f32x4*)(pb + 4) = od;
                }
            }
        }
    }
    __syncthreads();

    if (tid < 64) {
        int tm = tid >> 4, qg = (tid >> 2) & 3, g = tid & 3;
        float nn = 0.f, dd = 0.f;
#pragma unroll
        for (int w = 0; w < 4; ++w) {
            const float* pb = (const float*)(lds + O_RED + ((w * 4 + tm) * 4 + qg) * 32);
            nn += pb[g];
            dd += pb[4 + g];
        }
        agg[(size_t)n * 64 + tid] = nn / dd;
    }
}

// ---------------- Kernel C: out = relu(BN(agg@W2+b2) + skip) ----------------
__global__ __launch_bounds__(256) void fc2_kernel(
    const float* __restrict__ agg, const float* __restrict__ W2, const float* __restrict__ b2,
    const float* __restrict__ g2, const float* __restrict__ bb2,
    const float* __restrict__ m2, const float* __restrict__ v2,
    const float* __restrict__ skip, float* __restrict__ out)
{
    const int ROWS = 8;
    __shared__ float ar[ROWS][INNER];
    const int n0 = blockIdx.x * ROWS;
    const int t = threadIdx.x;

    for (int idx = t; idx < ROWS * INNER; idx += 256)
        ((float*)ar)[idx] = agg[(size_t)n0 * INNER + idx];
    __syncthreads();

    const float s2 = g2[t] * rsqrtf(v2[t] + EPSV);
    const float base = b2[t] - m2[t];
    const float bet = bb2[t];

    float accv[ROWS];
#pragma unroll
    for (int rr = 0; rr < ROWS; ++rr) accv[rr] = 0.f;
    for (int k = 0; k < INNER; ++k) {
        float wv = W2[(size_t)k * CC + t];
#pragma unroll
        for (int rr = 0; rr < ROWS; ++rr) accv[rr] = fmaf(ar[rr][k], wv, accv[rr]);
    }
#pragma unroll
    for (int rr = 0; rr < ROWS; ++rr) {
        float y = (accv[rr] + base) * s2 + bet;
        out[(size_t)(n0 + rr) * CC + t] =
            fmaxf(y + skip[(size_t)(n0 + rr) * CC + t], 0.f);
    }
}

extern "C" void kernel_launch(void* const* d_in, const int* in_sizes, int n_in,
                              void* d_out, int out_size, void* d_ws, size_t ws_size,
                              hipStream_t stream)
{
    const float* x   = (const float*)d_in[0];
    const float* r   = (const float*)d_in[1];
    const float* W1  = (const float*)d_in[2];
    const float* b1  = (const float*)d_in[3];
    const float* g1  = (const float*)d_in[4];
    const float* bb1 = (const float*)d_in[5];
    const float* m1  = (const float*)d_in[6];
    const float* v1  = (const float*)d_in[7];
    const float* Wqkv= (const float*)d_in[8];
    const float* Wt1 = (const float*)d_in[9];
    const float* bt1 = (const float*)d_in[10];
    const float* gt  = (const float*)d_in[11];
    const float* bbt = (const float*)d_in[12];
    const float* mt  = (const float*)d_in[13];
    const float* vt  = (const float*)d_in[14];
    const float* Wt2 = (const float*)d_in[15];
    const float* bt2 = (const float*)d_in[16];
    const float* Wa1 = (const float*)d_in[17];
    const float* ba1 = (const float*)d_in[18];
    const float* Wa2 = (const float*)d_in[19];
    const float* W2  = (const float*)d_in[21];
    const float* b2  = (const float*)d_in[22];
    const float* g2  = (const float*)d_in[23];
    const float* bb2 = (const float*)d_in[24];
    const float* m2  = (const float*)d_in[25];
    const float* v2  = (const float*)d_in[26];
    float* out = (float*)d_out;

    const int N = BB * TT;                 // 4096 rows
    float* skip = (float*)d_ws;            // N*256 floats = 4 MB
    float* qkv  = skip + (size_t)N * CC;   // N*192 floats = 3 MB
    float* agg  = qkv  + (size_t)N * 192;  // N*64  floats = 1 MB
    char*  img  = (char*)(agg + (size_t)N * 64);  // 22.7KB weight image

    prep_kernel<<<dim3(4), dim3(256), 0, stream>>>(
        Wt1, bt1, gt, bbt, mt, vt, Wt2, Wa1, Wa2, img);
    fc1_qkv_kernel<<<dim3(N / 8), dim3(256), 0, stream>>>(
        x, W1, b1, g1, bb1, m1, v1, Wqkv, skip, qkv);
    attn_mfma_kernel<<<dim3(N), dim3(256), 0, stream>>>(
        r, qkv, bt2, ba1, img, agg);
    fc2_kernel<<<dim3(N / 8), dim3(256), 0, stream>>>(
        agg, W2, b2, g2, bb2, m2, v2, skip, out);
}

// Round 17
// 183.045 us; speedup vs baseline: 1.6374x; 1.6374x over previous
//
#include <hip/hip_runtime.h>
#include <hip/hip_bf16.h>
#include <math.h>

#define BB 16
#define TT 256
#define CC 256
#define INNER 64
#define TPR 10
#define THD 32
#define EPSV 1e-5f

typedef __attribute__((ext_vector_type(8))) short short8;
typedef __attribute__((ext_vector_type(4))) float f32x4;
typedef __attribute__((ext_vector_type(4))) unsigned int u32x4;

__device__ __forceinline__ short f2bf(float f) {
    unsigned u = __float_as_uint(f);
    u += 0x7fffu + ((u >> 16) & 1);   // RNE
    return (short)(u >> 16);
}
__device__ __forceinline__ unsigned cvtpk(float a, float b) {
    __hip_bfloat162 h = __float22bfloat162_rn(float2{a, b});
    return *(unsigned*)&h;
}
__device__ __forceinline__ float bf_lo(unsigned u) { return __uint_as_float(u << 16); }
__device__ __forceinline__ float bf_hi(unsigned u) { return __uint_as_float(u & 0xffff0000u); }

// ---- weight image (in ws): WT1/c1 linear (read direct); WT2/WA1/WA2 PRE-SWIZZLED for LDS ----
#define IMG_WT1  0        // [32 m][32 k] bf16 linear (k>=10 zero)    2KB
#define IMG_WT2  2048     // [c>>1][128B] paired rows, mask-7 swizzle 4KB
#define IMG_WA1  6144     // [64 c][128B] mask-7 swizzle              8KB
#define IMG_WA2  14336    // [64 c][128B] mask-7 swizzle              8KB
#define IMG_C1   22528    // f32[32] folded BN bias                   128B
#define IMG_SZ   22656

__device__ __forceinline__ int sww(int pb, int key) {
    return ((pb & ~15) ^ key) | (pb & 15);
}

// ---------------- prep: bf16 weight images + folded BN ----------------
__global__ __launch_bounds__(256) void prep_kernel(
    const float* __restrict__ Wt1, const float* __restrict__ bt1,
    const float* __restrict__ gt, const float* __restrict__ bbt,
    const float* __restrict__ mt, const float* __restrict__ vt,
    const float* __restrict__ Wt2, const float* __restrict__ Wa1,
    const float* __restrict__ Wa2, char* __restrict__ img)
{
    const int blk = blockIdx.x, t = threadIdx.x;
    if (blk == 0) {
        for (int e = t; e < 32 * 32; e += 256) {
            int m = e >> 5, k = e & 31;
            float scv = gt[m] * rsqrtf(vt[m] + EPSV);
            float v = (k < TPR) ? Wt1[k * 32 + m] * scv : 0.f;
            *(short*)(img + IMG_WT1 + m * 64 + k * 2) = f2bf(v);
        }
        if (t < 32) {
            float scv = gt[t] * rsqrtf(vt[t] + EPSV);
            ((float*)(img + IMG_C1))[t] = (bt1[t] - mt[t]) * scv + bbt[t];
        }
    } else if (blk == 1) {
        for (int e = t; e < 32 * 64; e += 256) {
            int h = e >> 6, c = e & 63;
            int off = IMG_WT2 + (c >> 1) * 128 + sww((c & 1) * 64 + h * 2, ((c >> 1) & 7) << 4);
            *(short*)(img + off) = f2bf(Wt2[e]);
        }
    } else {
        const float* W = (blk == 2) ? Wa1 : Wa2;
        int base = (blk == 2) ? IMG_WA1 : IMG_WA2;
        for (int e = t; e < 64 * 64; e += 256) {
            int k = e >> 6, c = e & 63;
            int off = base + c * 128 + sww(k * 2, (c & 7) << 4);
            *(short*)(img + off) = f2bf(W[e]);
        }
    }
}

// ---------------- Kernel A: y = BN(x@W1+b1); skip=y; qkv = relu(y)@Wqkv ----------------
__global__ __launch_bounds__(256) void fc1_qkv_kernel(
    const float* __restrict__ x, const float* __restrict__ W1, const float* __restrict__ b1,
    const float* __restrict__ g1, const float* __restrict__ bb1,
    const float* __restrict__ m1, const float* __restrict__ v1,
    const float* __restrict__ Wqkv,
    float* __restrict__ skip, float* __restrict__ qkv)
{
    const int ROWS = 8;
    __shared__ float xr[ROWS][CC];
    __shared__ float yr[ROWS][CC];
    const int n0 = blockIdx.x * ROWS;
    const int t = threadIdx.x;

#pragma unroll
    for (int rr = 0; rr < ROWS; ++rr)
        xr[rr][t] = x[(size_t)(n0 + rr) * CC + t];
    __syncthreads();

    float acc[ROWS];
#pragma unroll
    for (int rr = 0; rr < ROWS; ++rr) acc[rr] = 0.f;
    for (int k = 0; k < CC; ++k) {
        float wv = W1[(size_t)k * CC + t];
#pragma unroll
        for (int rr = 0; rr < ROWS; ++rr) acc[rr] = fmaf(xr[rr][k], wv, acc[rr]);
    }
    const float s1 = g1[t] * rsqrtf(v1[t] + EPSV);
    const float base = b1[t] - m1[t];
    const float bet = bb1[t];
#pragma unroll
    for (int rr = 0; rr < ROWS; ++rr) {
        float y = (acc[rr] + base) * s1 + bet;
        skip[(size_t)(n0 + rr) * CC + t] = y;
        yr[rr][t] = fmaxf(y, 0.f);
    }
    __syncthreads();

    if (t < 192) {
        float a2[ROWS];
#pragma unroll
        for (int rr = 0; rr < ROWS; ++rr) a2[rr] = 0.f;
        for (int k = 0; k < CC; ++k) {
            float wv = Wqkv[(size_t)k * 192 + t];
#pragma unroll
            for (int rr = 0; rr < ROWS; ++rr) a2[rr] = fmaf(yr[rr][k], wv, a2[rr]);
        }
#pragma unroll
        for (int rr = 0; rr < ROWS; ++rr)
            qkv[(size_t)(n0 + rr) * 192 + t] = a2[rr];
    }
}

// ---------------- Kernel B: MFMA fused vector-attention (R9 body, 68KB LDS) ----------------
#define O_R    0        // r: [256 j][48B stride] bf16 (10 real + pad to 24 slots), no swizzle
#define O_TH   12288    // [256 j][128B] mask-7: hid -> t -> h2 (wave-local reuse)
#define O_WT2  45056    // 4KB  paired rows mask-7  (contiguous with WA1/WA2: 20KB staged)
#define O_WA1  49152    // 8KB
#define O_WA2  57344    // 8KB
#define O_RED  65536    // 4KB
#define LDSZ   69632    // 68KB -> 2 blocks/CU

__device__ __forceinline__ int swb(int row, int cb) {
    return (row << 7) + (((cb & ~15) ^ ((row & 7) << 4)) | (cb & 15));
}
__device__ __forceinline__ short8 ldfrag(const char* lds, int base, int row, int cb16) {
    return *(const short8*)(lds + base + (row << 7) + (cb16 ^ ((row & 7) << 4)));
}

__global__ __launch_bounds__(512, 2) void attn_mfma_kernel(
    const float* __restrict__ r, const float* __restrict__ qkv,
    const float* __restrict__ bt2, const float* __restrict__ ba1,
    const char* __restrict__ img, float* __restrict__ agg)
{
    __shared__ __align__(16) char lds[LDSZ];
    const int n = blockIdx.x, b = n >> 8;
    const int tid = threadIdx.x;
    const int wv = tid >> 6, lane = tid & 63;
    const int lid = lane & 15, q4 = lane >> 4;
    const int kb = q4 * 16;
    const int jt0 = wv * 2;

    const float* kvb = qkv + (size_t)b * (TT * 192);
    const f32x4 z4 = {0.f, 0.f, 0.f, 0.f};

    // ---- async weight staging: 20 x 1KB (WT2|WA1|WA2, pre-swizzled, contiguous)
#pragma unroll
    for (int ci = 0; ci < 3; ++ci) {
        int c = wv + ci * 8;
        if (c < 20) {
            __builtin_amdgcn_global_load_lds(
                (const __attribute__((address_space(1))) unsigned*)(const unsigned*)(img + IMG_WT2 + c * 1024 + lane * 16),
                (__attribute__((address_space(3))) unsigned*)(unsigned*)(lds + O_WT2 + c * 1024 + lane * 16),
                16, 0, 0);
        }
    }

    // ---- hoisted q,k loads (land during r-staging / GEMM1)
    f32x4 qv4[4], k4[4][2];
#pragma unroll
    for (int tm = 0; tm < 4; ++tm) {
        int ch0 = tm * 16 + q4 * 4;
        qv4[tm] = *(const f32x4*)(qkv + (size_t)n * 192 + ch0);
#pragma unroll
        for (int tn = 0; tn < 2; ++tn) {
            int j = (jt0 + tn) * 16 + lid;
            k4[tm][tn] = *(const f32x4*)(kvb + (size_t)j * 192 + 64 + ch0);
        }
    }

    // ---- r staging: lane pair (j, half): 16B-aligned stores, stride-48 rows
    {
        const float* rrow = r + (size_t)n * (TT * TPR);
        int j = tid >> 1, hf = tid & 1;
        const float* rp = rrow + j * TPR + hf * 5;
        float v0 = rp[0], v1 = rp[1], v2 = rp[2], v3 = rp[3], v4 = rp[4];
        float o0 = __shfl_xor(v0, 1);
        float o1 = __shfl_xor(v1, 1);
        float o2 = __shfl_xor(v2, 1);
        char* rb = lds + O_R + j * 48;
        if (hf == 0) {
            u32x4 c;
            c[0] = cvtpk(v0, v1); c[1] = cvtpk(v2, v3);
            c[2] = cvtpk(v4, o0); c[3] = cvtpk(o1, o2);
            *(u32x4*)(rb) = c;
        } else {
            u32x4 c;
            c[0] = cvtpk(v3, v4); c[1] = 0u; c[2] = 0u; c[3] = 0u;
            *(u32x4*)(rb + 16) = c;
            u32x4 z; z[0] = 0u; z[1] = 0u; z[2] = 0u; z[3] = 0u;
            *(u32x4*)(rb + 32) = z;
        }
    }
    __syncthreads();
    // ---------- wave-local from here until final reduction ----------

    // ---- GEMM1: hid = relu(Wt1f^T @ r^T + c1); A,C direct from img (L2-hot)
    {
        short8 a10 = *(const short8*)(img + IMG_WT1 + lid * 64 + kb);
        short8 a11 = *(const short8*)(img + IMG_WT1 + (16 + lid) * 64 + kb);
        const float* c1g = (const float*)(img + IMG_C1);
        f32x4 c1v0 = *(const f32x4*)(c1g + q4 * 4);
        f32x4 c1v1 = *(const f32x4*)(c1g + 16 + q4 * 4);
        f32x4 acc1[2][2];
#pragma unroll
        for (int tn = 0; tn < 2; ++tn) {
            int j = (jt0 + tn) * 16 + lid;
            // rows hold K=0..23 (10 real + zeros); q4>=2 slices are all zero
            union { short8 s8; u32x4 u; } bf;
            bf.u[0] = 0u; bf.u[1] = 0u; bf.u[2] = 0u; bf.u[3] = 0u;
            if (q4 < 2)
                bf.s8 = *(const short8*)(lds + O_R + j * 48 + kb);
            acc1[0][tn] = __builtin_amdgcn_mfma_f32_16x16x32_bf16(a10, bf.s8, c1v0, 0, 0, 0);
            acc1[1][tn] = __builtin_amdgcn_mfma_f32_16x16x32_bf16(a11, bf.s8, c1v1, 0, 0, 0);
        }
#pragma unroll
        for (int tm = 0; tm < 2; ++tm)
#pragma unroll
            for (int tn = 0; tn < 2; ++tn) {
                int j = (jt0 + tn) * 16 + lid;
                uint2 w;
                w.x = cvtpk(fmaxf(acc1[tm][tn][0], 0.f), fmaxf(acc1[tm][tn][1], 0.f));
                w.y = cvtpk(fmaxf(acc1[tm][tn][2], 0.f), fmaxf(acc1[tm][tn][3], 0.f));
                *(uint2*)(lds + O_TH + swb(j, tm * 32 + q4 * 8)) = w;
            }
    }

    // ---- pack pk = q - k to bf16 (q,k die here)
    uint2 pk[4][2];
#pragma unroll
    for (int tm = 0; tm < 4; ++tm)
#pragma unroll
        for (int tn = 0; tn < 2; ++tn) {
            pk[tm][tn].x = cvtpk(qv4[tm][0] - k4[tm][tn][0], qv4[tm][1] - k4[tm][tn][1]);
            pk[tm][tn].y = cvtpk(qv4[tm][2] - k4[tm][tn][2], qv4[tm][3] - k4[tm][tn][3]);
        }

    // ---- issue v loads (consumed at t-epilogue) + bt2 C-init
    f32x4 v4h[4][2], bt2v[4];
#pragma unroll
    for (int tm = 0; tm < 4; ++tm) {
        int ch0 = tm * 16 + q4 * 4;
        bt2v[tm] = *(const f32x4*)(bt2 + ch0);
#pragma unroll
        for (int tn = 0; tn < 2; ++tn) {
            int j = (jt0 + tn) * 16 + lid;
            v4h[tm][tn] = *(const f32x4*)(kvb + (size_t)j * 192 + 128 + ch0);
        }
    }

    // ---- GEMM2: rel = Wt2^T @ hid^T + bt2 (in C)
    f32x4 rel[4][2];
    {
        short8 bfh[2];
#pragma unroll
        for (int tn = 0; tn < 2; ++tn)
            bfh[tn] = ldfrag(lds, O_TH, (jt0 + tn) * 16 + lid, kb);
#pragma unroll
        for (int tm = 0; tm < 4; ++tm) {
            int c = tm * 16 + lid;
            short8 aw = ldfrag(lds, O_WT2, c >> 1, (c & 1) * 64 + kb);
#pragma unroll
            for (int tn = 0; tn < 2; ++tn)
                rel[tm][tn] = __builtin_amdgcn_mfma_f32_16x16x32_bf16(aw, bfh[tn], bt2v[tm], 0, 0, 0);
        }
    }

    // ---- t-epilogue: t = pk + rel -> bf16 LDS;  vvp = bf16(v + rel) (rel, v die)
    uint2 vvp[4][2];
#pragma unroll
    for (int tm = 0; tm < 4; ++tm)
#pragma unroll
        for (int tn = 0; tn < 2; ++tn) {
            int j = (jt0 + tn) * 16 + lid;
            float r0 = rel[tm][tn][0], r1 = rel[tm][tn][1];
            float r2 = rel[tm][tn][2], r3 = rel[tm][tn][3];
            float t0 = bf_lo(pk[tm][tn].x) + r0;
            float t1 = bf_hi(pk[tm][tn].x) + r1;
            float t2 = bf_lo(pk[tm][tn].y) + r2;
            float t3 = bf_hi(pk[tm][tn].y) + r3;
            uint2 w; w.x = cvtpk(t0, t1); w.y = cvtpk(t2, t3);
            *(uint2*)(lds + O_TH + swb(j, tm * 32 + q4 * 8)) = w;
            vvp[tm][tn].x = cvtpk(v4h[tm][tn][0] + r0, v4h[tm][tn][1] + r1);
            vvp[tm][tn].y = cvtpk(v4h[tm][tn][2] + r2, v4h[tm][tn][3] + r3);
        }

    // ---- GEMM3: h2 = relu(Wa1^T @ t^T + ba1 (in C))
    f32x4 ba1v[4];
#pragma unroll
    for (int tm = 0; tm < 4; ++tm)
        ba1v[tm] = *(const f32x4*)(ba1 + tm * 16 + q4 * 4);
    f32x4 acc[4][2];
#pragma unroll
    for (int tm = 0; tm < 4; ++tm)
#pragma unroll
        for (int tn = 0; tn < 2; ++tn) acc[tm][tn] = ba1v[tm];
#pragma unroll
    for (int ks = 0; ks < 2; ++ks) {
        short8 aw[4];
#pragma unroll
        for (int tm = 0; tm < 4; ++tm)
            aw[tm] = ldfrag(lds, O_WA1, tm * 16 + lid, ks * 64 + kb);
#pragma unroll
        for (int tn = 0; tn < 2; ++tn) {
            short8 bt = ldfrag(lds, O_TH, (jt0 + tn) * 16 + lid, ks * 64 + kb);
#pragma unroll
            for (int tm = 0; tm < 4; ++tm)
                acc[tm][tn] = __builtin_amdgcn_mfma_f32_16x16x32_bf16(aw[tm], bt, acc[tm][tn], 0, 0, 0);
        }
    }
#pragma unroll
    for (int tm = 0; tm < 4; ++tm)
#pragma unroll
        for (int tn = 0; tn < 2; ++tn) {
            int j = (jt0 + tn) * 16 + lid;
            uint2 w;
            w.x = cvtpk(fmaxf(acc[tm][tn][0], 0.f), fmaxf(acc[tm][tn][1], 0.f));
            w.y = cvtpk(fmaxf(acc[tm][tn][2], 0.f), fmaxf(acc[tm][tn][3], 0.f));
            *(uint2*)(lds + O_TH + swb(j, tm * 32 + q4 * 8)) = w;
        }

    // ---- GEMM4: sim = Wa2^T @ h2^T (ba2 cancels in softmax)
#pragma unroll
    for (int tm = 0; tm < 4; ++tm)
#pragma unroll
        for (int tn = 0; tn < 2; ++tn) acc[tm][tn] = z4;
#pragma unroll
    for (int ks = 0; ks < 2; ++ks) {
        short8 aw[4];
#pragma unroll
        for (int tm = 0; tm < 4; ++tm)
            aw[tm] = ldfrag(lds, O_WA2, tm * 16 + lid, ks * 64 + kb);
#pragma unroll
        for (int tn = 0; tn < 2; ++tn) {
            short8 bt = ldfrag(lds, O_TH, (jt0 + tn) * 16 + lid, ks * 64 + kb);
#pragma unroll
            for (int tm = 0; tm < 4; ++tm)
                acc[tm][tn] = __builtin_amdgcn_mfma_f32_16x16x32_bf16(aw[tm], bt, acc[tm][tn], 0, 0, 0);
        }
    }

    // ---- softmax over j + weighted vv sum
#pragma unroll
    for (int tm = 0; tm < 4; ++tm) {
        f32x4 num = z4, den = z4;
#pragma unroll
        for (int tn = 0; tn < 2; ++tn) {
            float vf0 = bf_lo(vvp[tm][tn].x), vf1 = bf_hi(vvp[tm][tn].x);
            float vf2 = bf_lo(vvp[tm][tn].y), vf3 = bf_hi(vvp[tm][tn].y);
            float e0 = __expf(acc[tm][tn][0]);
            float e1 = __expf(acc[tm][tn][1]);
            float e2 = __expf(acc[tm][tn][2]);
            float e3 = __expf(acc[tm][tn][3]);
            den[0] += e0; num[0] = fmaf(e0, vf0, num[0]);
            den[1] += e1; num[1] = fmaf(e1, vf1, num[1]);
            den[2] += e2; num[2] = fmaf(e2, vf2, num[2]);
            den[3] += e3; num[3] = fmaf(e3, vf3, num[3]);
        }
#pragma unroll
        for (int ofs = 1; ofs < 16; ofs <<= 1) {
#pragma unroll
            for (int g = 0; g < 4; ++g) {
                num[g] += __shfl_xor(num[g], ofs);
                den[g] += __shfl_xor(den[g], ofs);
            }
        }
        if (lid == 0) {
            int base = O_RED + ((wv * 4 + tm) * 4 + q4) * 32;
            *(f32x4*)(lds + base) = num;
            *(f32x4*)(lds + base + 16) = den;
        }
    }
    __syncthreads();

    if (tid < 64) {
        int tm = tid >> 4, qq = (tid >> 2) & 3, g = tid & 3;
        float nn = 0.f, dd = 0.f;
#pragma unroll
        for (int w = 0; w < 8; ++w) {
            int base = O_RED + ((w * 4 + tm) * 4 + qq) * 32 + g * 4;
            nn += *(const float*)(lds + base);
            dd += *(const float*)(lds + base + 16);
        }
        agg[(size_t)n * 64 + tid] = nn / dd;
    }
}

// ---------------- Kernel C: out = relu(BN(agg@W2+b2) + skip) ----------------
__global__ __launch_bounds__(256) void fc2_kernel(
    const float* __restrict__ agg, const float* __restrict__ W2, const float* __restrict__ b2,
    const float* __restrict__ g2, const float* __restrict__ bb2,
    const float* __restrict__ m2, const float* __restrict__ v2,
    const float* __restrict__ skip, float* __restrict__ out)
{
    const int ROWS = 8;
    __shared__ float ar[ROWS][INNER];
    const int n0 = blockIdx.x * ROWS;
    const int t = threadIdx.x;

    for (int idx = t; idx < ROWS * INNER; idx += 256)
        ((float*)ar)[idx] = agg[(size_t)n0 * INNER + idx];
    __syncthreads();

    const float s2 = g2[t] * rsqrtf(v2[t] + EPSV);
    const float base = b2[t] - m2[t];
    const float bet = bb2[t];

    float accv[ROWS];
#pragma unroll
    for (int rr = 0; rr < ROWS; ++rr) accv[rr] = 0.f;
    for (int k = 0; k < INNER; ++k) {
        float wv = W2[(size_t)k * CC + t];
#pragma unroll
        for (int rr = 0; rr < ROWS; ++rr) accv[rr] = fmaf(ar[rr][k], wv, accv[rr]);
    }
#pragma unroll
    for (int rr = 0; rr < ROWS; ++rr) {
        float y = (accv[rr] + base) * s2 + bet;
        out[(size_t)(n0 + rr) * CC + t] =
            fmaxf(y + skip[(size_t)(n0 + rr) * CC + t], 0.f);
    }
}

extern "C" void kernel_launch(void* const* d_in, const int* in_sizes, int n_in,
                              void* d_out, int out_size, void* d_ws, size_t ws_size,
                              hipStream_t stream)
{
    const float* x   = (const float*)d_in[0];
    const float* r   = (const float*)d_in[1];
    const float* W1  = (const float*)d_in[2];
    const float* b1  = (const float*)d_in[3];
    const float* g1  = (const float*)d_in[4];
    const float* bb1 = (const float*)d_in[5];
    const float* m1  = (const float*)d_in[6];
    const float* v1  = (const float*)d_in[7];
    const float* Wqkv= (const float*)d_in[8];
    const float* Wt1 = (const float*)d_in[9];
    const float* bt1 = (const float*)d_in[10];
    const float* gt  = (const float*)d_in[11];
    const float* bbt = (const float*)d_in[12];
    const float* mt  = (const float*)d_in[13];
    const float* vt  = (const float*)d_in[14];
    const float* Wt2 = (const float*)d_in[15];
    const float* bt2 = (const float*)d_in[16];
    const float* Wa1 = (const float*)d_in[17];
    const float* ba1 = (const float*)d_in[18];
    const float* Wa2 = (const float*)d_in[19];
    const float* W2  = (const float*)d_in[21];
    const float* b2  = (const float*)d_in[22];
    const float* g2  = (const float*)d_in[23];
    const float* bb2 = (const float*)d_in[24];
    const float* m2  = (const float*)d_in[25];
    const float* v2  = (const float*)d_in[26];
    float* out = (float*)d_out;

    const int N = BB * TT;                 // 4096 rows
    float* skip = (float*)d_ws;            // N*256 floats
    float* qkv  = skip + (size_t)N * CC;   // N*192 floats
    float* agg  = qkv  + (size_t)N * 192;  // N*64  floats
    char*  img  = (char*)(agg + (size_t)N * 64);  // 22.7KB weight image

    prep_kernel<<<dim3(4), dim3(256), 0, stream>>>(
        Wt1, bt1, gt, bbt, mt, vt, Wt2, Wa1, Wa2, img);
    fc1_qkv_kernel<<<dim3(N / 8), dim3(256), 0, stream>>>(
        x, W1, b1, g1, bb1, m1, v1, Wqkv, skip, qkv);
    attn_mfma_kernel<<<dim3(N), dim3(512), 0, stream>>>(
        r, qkv, bt2, ba1, img, agg);
    fc2_kernel<<<dim3(N / 8), dim3(256), 0, stream>>>(
        agg, W2, b2, g2, bb2, m2, v2, skip, out);
}

// Round 18
// 144.845 us; speedup vs baseline: 2.0693x; 1.2637x over previous
//
#include <hip/hip_runtime.h>
#include <hip/hip_bf16.h>
#include <math.h>

#define BB 16
#define TT 256
#define CC 256
#define INNER 64
#define TPR 10
#define THD 32
#define EPSV 1e-5f

typedef __attribute__((ext_vector_type(8))) short short8;
typedef __attribute__((ext_vector_type(4))) float f32x4;
typedef __attribute__((ext_vector_type(4))) unsigned int u32x4;

__device__ __forceinline__ short f2bf(float f) {
    unsigned u = __float_as_uint(f);
    u += 0x7fffu + ((u >> 16) & 1);   // RNE
    return (short)(u >> 16);
}
__device__ __forceinline__ unsigned cvtpk(float a, float b) {
    __hip_bfloat162 h = __float22bfloat162_rn(float2{a, b});
    return *(unsigned*)&h;
}
__device__ __forceinline__ float bf_lo(unsigned u) { return __uint_as_float(u << 16); }
__device__ __forceinline__ float bf_hi(unsigned u) { return __uint_as_float(u & 0xffff0000u); }

// ---- weight image (in ws): WT1/c1 linear (read direct); WT2/WA1/WA2 PRE-SWIZZLED for LDS ----
#define IMG_WT1  0        // [32 m][32 k] bf16 linear (k>=10 zero)    2KB
#define IMG_WT2  2048     // [c>>1][128B] paired rows, mask-7 swizzle 4KB
#define IMG_WA1  6144     // [64 c][128B] mask-7 swizzle              8KB
#define IMG_WA2  14336    // [64 c][128B] mask-7 swizzle              8KB
#define IMG_C1   22528    // f32[32] folded BN bias                   128B
#define IMG_SZ   22656

__device__ __forceinline__ int sww(int pb, int key) {
    return ((pb & ~15) ^ key) | (pb & 15);
}

// ---------------- prep: bf16 weight images + folded BN ----------------
__global__ __launch_bounds__(256) void prep_kernel(
    const float* __restrict__ Wt1, const float* __restrict__ bt1,
    const float* __restrict__ gt, const float* __restrict__ bbt,
    const float* __restrict__ mt, const float* __restrict__ vt,
    const float* __restrict__ Wt2, const float* __restrict__ Wa1,
    const float* __restrict__ Wa2, char* __restrict__ img)
{
    const int blk = blockIdx.x, t = threadIdx.x;
    if (blk == 0) {
        for (int e = t; e < 32 * 32; e += 256) {
            int m = e >> 5, k = e & 31;
            float scv = gt[m] * rsqrtf(vt[m] + EPSV);
            float v = (k < TPR) ? Wt1[k * 32 + m] * scv : 0.f;
            *(short*)(img + IMG_WT1 + m * 64 + k * 2) = f2bf(v);
        }
        if (t < 32) {
            float scv = gt[t] * rsqrtf(vt[t] + EPSV);
            ((float*)(img + IMG_C1))[t] = (bt1[t] - mt[t]) * scv + bbt[t];
        }
    } else if (blk == 1) {
        for (int e = t; e < 32 * 64; e += 256) {
            int h = e >> 6, c = e & 63;
            int off = IMG_WT2 + (c >> 1) * 128 + sww((c & 1) * 64 + h * 2, ((c >> 1) & 7) << 4);
            *(short*)(img + off) = f2bf(Wt2[e]);
        }
    } else {
        const float* W = (blk == 2) ? Wa1 : Wa2;
        int base = (blk == 2) ? IMG_WA1 : IMG_WA2;
        for (int e = t; e < 64 * 64; e += 256) {
            int k = e >> 6, c = e & 63;
            int off = base + c * 128 + sww(k * 2, (c & 7) << 4);
            *(short*)(img + off) = f2bf(W[e]);
        }
    }
}

// ---------------- Kernel A: y = BN(x@W1+b1); skip=y; qkv = relu(y)@Wqkv ----------------
__global__ __launch_bounds__(256) void fc1_qkv_kernel(
    const float* __restrict__ x, const float* __restrict__ W1, const float* __restrict__ b1,
    const float* __restrict__ g1, const float* __restrict__ bb1,
    const float* __restrict__ m1, const float* __restrict__ v1,
    const float* __restrict__ Wqkv,
    float* __restrict__ skip, float* __restrict__ qkv)
{
    const int ROWS = 8;
    __shared__ float xr[ROWS][CC];
    __shared__ float yr[ROWS][CC];
    const int n0 = blockIdx.x * ROWS;
    const int t = threadIdx.x;

#pragma unroll
    for (int rr = 0; rr < ROWS; ++rr)
        xr[rr][t] = x[(size_t)(n0 + rr) * CC + t];
    __syncthreads();

    float acc[ROWS];
#pragma unroll
    for (int rr = 0; rr < ROWS; ++rr) acc[rr] = 0.f;
    for (int k = 0; k < CC; ++k) {
        float wv = W1[(size_t)k * CC + t];
#pragma unroll
        for (int rr = 0; rr < ROWS; ++rr) acc[rr] = fmaf(xr[rr][k], wv, acc[rr]);
    }
    const float s1 = g1[t] * rsqrtf(v1[t] + EPSV);
    const float base = b1[t] - m1[t];
    const float bet = bb1[t];
#pragma unroll
    for (int rr = 0; rr < ROWS; ++rr) {
        float y = (acc[rr] + base) * s1 + bet;
        skip[(size_t)(n0 + rr) * CC + t] = y;
        yr[rr][t] = fmaxf(y, 0.f);
    }
    __syncthreads();

    if (t < 192) {
        float a2[ROWS];
#pragma unroll
        for (int rr = 0; rr < ROWS; ++rr) a2[rr] = 0.f;
        for (int k = 0; k < CC; ++k) {
            float wv = Wqkv[(size_t)k * 192 + t];
#pragma unroll
            for (int rr = 0; rr < ROWS; ++rr) a2[rr] = fmaf(yr[rr][k], wv, a2[rr]);
        }
#pragma unroll
        for (int rr = 0; rr < ROWS; ++rr)
            qkv[(size_t)(n0 + rr) * 192 + t] = a2[rr];
    }
}

// ---------------- Kernel B: MFMA fused vector-attention ----------------
// grid = 8192: (b,i) x 2 j-halves; block = 256 (4 waves); each wave owns 32 j-rows
// (tn=2, R17's exact single-pass body -> same 68-reg no-spill profile). 4-wave
// blocks quantize residency finely: ~132 total regs -> 3 waves/SIMD -> 3 blocks/CU.
// Softmax over j is a pure sum: each block emits num/den partials for its half.
#define O_R    0        // r: [128 j][48B stride] bf16, no swizzle          6KB
#define O_TH   6144     // [128 j][128B] mask-7: hid -> t -> h2             16KB
#define O_WT2  22528    // 4KB  paired rows mask-7 (WT2|WA1|WA2 contiguous: 20KB)
#define O_WA1  26624    // 8KB
#define O_WA2  34816    // 8KB
#define O_RED  43008    // 4 waves x 4 tm x 4 q4 x 32B = 2KB
#define LDSZ   45056    // 44KB -> 3 blocks/CU LDS-wise

__device__ __forceinline__ int swb(int row, int cb) {
    return (row << 7) + (((cb & ~15) ^ ((row & 7) << 4)) | (cb & 15));
}
__device__ __forceinline__ short8 ldfrag(const char* lds, int base, int row, int cb16) {
    return *(const short8*)(lds + base + (row << 7) + (cb16 ^ ((row & 7) << 4)));
}

__global__ __launch_bounds__(256, 2) void attn_mfma_kernel(
    const float* __restrict__ r, const float* __restrict__ qkv,
    const float* __restrict__ bt2, const float* __restrict__ ba1,
    const char* __restrict__ img, float* __restrict__ part)
{
    __shared__ __align__(16) char lds[LDSZ];
    const int blk = blockIdx.x;
    const int n = blk >> 1, hf2 = blk & 1, b = n >> 8;
    const int jbase = hf2 * 128;
    const int tid = threadIdx.x;
    const int wv = tid >> 6, lane = tid & 63;
    const int lid = lane & 15, q4 = lane >> 4;
    const int kb = q4 * 16;
    const int jt0 = wv * 2;            // wave's first local 16-row tile (local rows wv*32..+32)

    const float* kvb = qkv + (size_t)b * (TT * 192);
    const f32x4 z4 = {0.f, 0.f, 0.f, 0.f};

    // ---- async weight staging: 20 x 1KB (WT2|WA1|WA2, pre-swizzled, contiguous)
#pragma unroll
    for (int ci = 0; ci < 5; ++ci) {
        int c = wv + ci * 4;
        __builtin_amdgcn_global_load_lds(
            (const __attribute__((address_space(1))) unsigned*)(const unsigned*)(img + IMG_WT2 + c * 1024 + lane * 16),
            (__attribute__((address_space(3))) unsigned*)(unsigned*)(lds + O_WT2 + c * 1024 + lane * 16),
            16, 0, 0);
    }

    // ---- hoisted q,k loads (land during r-staging / GEMM1)
    f32x4 qv4[4], k4[4][2];
#pragma unroll
    for (int tm = 0; tm < 4; ++tm) {
        int ch0 = tm * 16 + q4 * 4;
        qv4[tm] = *(const f32x4*)(qkv + (size_t)n * 192 + ch0);
#pragma unroll
        for (int tn = 0; tn < 2; ++tn) {
            int jg = jbase + (jt0 + tn) * 16 + lid;
            k4[tm][tn] = *(const f32x4*)(kvb + (size_t)jg * 192 + 64 + ch0);
        }
    }

    // ---- r staging: lane pair (local j, half): 16B-aligned stores, stride-48 rows
    {
        const float* rrow = r + (size_t)n * (TT * TPR);
        int j = tid >> 1, hf = tid & 1;        // local j 0..127
        const float* rp = rrow + (size_t)(jbase + j) * TPR + hf * 5;
        float v0 = rp[0], v1 = rp[1], v2 = rp[2], v3 = rp[3], v4 = rp[4];
        float o0 = __shfl_xor(v0, 1);
        float o1 = __shfl_xor(v1, 1);
        float o2 = __shfl_xor(v2, 1);
        char* rb = lds + O_R + j * 48;
        if (hf == 0) {
            u32x4 c;
            c[0] = cvtpk(v0, v1); c[1] = cvtpk(v2, v3);
            c[2] = cvtpk(v4, o0); c[3] = cvtpk(o1, o2);
            *(u32x4*)(rb) = c;
        } else {
            u32x4 c;
            c[0] = cvtpk(v3, v4); c[1] = 0u; c[2] = 0u; c[3] = 0u;
            *(u32x4*)(rb + 16) = c;
            u32x4 z; z[0] = 0u; z[1] = 0u; z[2] = 0u; z[3] = 0u;
            *(u32x4*)(rb + 32) = z;
        }
    }
    __syncthreads();
    // ---------- wave-local from here until final reduction ----------

    // ---- GEMM1: hid = relu(Wt1f^T @ r^T + c1); A,C direct from img (L2-hot)
    {
        short8 a10 = *(const short8*)(img + IMG_WT1 + lid * 64 + kb);
        short8 a11 = *(const short8*)(img + IMG_WT1 + (16 + lid) * 64 + kb);
        const float* c1g = (const float*)(img + IMG_C1);
        f32x4 c1v0 = *(const f32x4*)(c1g + q4 * 4);
        f32x4 c1v1 = *(const f32x4*)(c1g + 16 + q4 * 4);
        f32x4 acc1[2][2];
#pragma unroll
        for (int tn = 0; tn < 2; ++tn) {
            int j = (jt0 + tn) * 16 + lid;     // local row
            union { short8 s8; u32x4 u; } bf;
            bf.u[0] = 0u; bf.u[1] = 0u; bf.u[2] = 0u; bf.u[3] = 0u;
            if (q4 < 2)
                bf.s8 = *(const short8*)(lds + O_R + j * 48 + kb);
            acc1[0][tn] = __builtin_amdgcn_mfma_f32_16x16x32_bf16(a10, bf.s8, c1v0, 0, 0, 0);
            acc1[1][tn] = __builtin_amdgcn_mfma_f32_16x16x32_bf16(a11, bf.s8, c1v1, 0, 0, 0);
        }
#pragma unroll
        for (int tm = 0; tm < 2; ++tm)
#pragma unroll
            for (int tn = 0; tn < 2; ++tn) {
                int j = (jt0 + tn) * 16 + lid;
                uint2 w;
                w.x = cvtpk(fmaxf(acc1[tm][tn][0], 0.f), fmaxf(acc1[tm][tn][1], 0.f));
                w.y = cvtpk(fmaxf(acc1[tm][tn][2], 0.f), fmaxf(acc1[tm][tn][3], 0.f));
                *(uint2*)(lds + O_TH + swb(j, tm * 32 + q4 * 8)) = w;
            }
    }

    // ---- pack pk = q - k to bf16 (q,k die here)
    uint2 pk[4][2];
#pragma unroll
    for (int tm = 0; tm < 4; ++tm)
#pragma unroll
        for (int tn = 0; tn < 2; ++tn) {
            pk[tm][tn].x = cvtpk(qv4[tm][0] - k4[tm][tn][0], qv4[tm][1] - k4[tm][tn][1]);
            pk[tm][tn].y = cvtpk(qv4[tm][2] - k4[tm][tn][2], qv4[tm][3] - k4[tm][tn][3]);
        }

    // ---- issue v loads (consumed at t-epilogue) + bt2 C-init
    f32x4 v4h[4][2], bt2v[4];
#pragma unroll
    for (int tm = 0; tm < 4; ++tm) {
        int ch0 = tm * 16 + q4 * 4;
        bt2v[tm] = *(const f32x4*)(bt2 + ch0);
#pragma unroll
        for (int tn = 0; tn < 2; ++tn) {
            int jg = jbase + (jt0 + tn) * 16 + lid;
            v4h[tm][tn] = *(const f32x4*)(kvb + (size_t)jg * 192 + 128 + ch0);
        }
    }

    // ---- GEMM2: rel = Wt2^T @ hid^T + bt2 (in C)
    f32x4 rel[4][2];
    {
        short8 bfh[2];
#pragma unroll
        for (int tn = 0; tn < 2; ++tn)
            bfh[tn] = ldfrag(lds, O_TH, (jt0 + tn) * 16 + lid, kb);
#pragma unroll
        for (int tm = 0; tm < 4; ++tm) {
            int c = tm * 16 + lid;
            short8 aw = ldfrag(lds, O_WT2, c >> 1, (c & 1) * 64 + kb);
#pragma unroll
            for (int tn = 0; tn < 2; ++tn)
                rel[tm][tn] = __builtin_amdgcn_mfma_f32_16x16x32_bf16(aw, bfh[tn], bt2v[tm], 0, 0, 0);
        }
    }

    // ---- t-epilogue: t = pk + rel -> bf16 LDS;  vvp = bf16(v + rel) (rel, v die)
    uint2 vvp[4][2];
#pragma unroll
    for (int tm = 0; tm < 4; ++tm)
#pragma unroll
        for (int tn = 0; tn < 2; ++tn) {
            int j = (jt0 + tn) * 16 + lid;
            float r0 = rel[tm][tn][0], r1 = rel[tm][tn][1];
            float r2 = rel[tm][tn][2], r3 = rel[tm][tn][3];
            float t0 = bf_lo(pk[tm][tn].x) + r0;
            float t1 = bf_hi(pk[tm][tn].x) + r1;
            float t2 = bf_lo(pk[tm][tn].y) + r2;
            float t3 = bf_hi(pk[tm][tn].y) + r3;
            uint2 w; w.x = cvtpk(t0, t1); w.y = cvtpk(t2, t3);
            *(uint2*)(lds + O_TH + swb(j, tm * 32 + q4 * 8)) = w;
            vvp[tm][tn].x = cvtpk(v4h[tm][tn][0] + r0, v4h[tm][tn][1] + r1);
            vvp[tm][tn].y = cvtpk(v4h[tm][tn][2] + r2, v4h[tm][tn][3] + r3);
        }

    // ---- GEMM3: h2 = relu(Wa1^T @ t^T + ba1 (in C))
    f32x4 ba1v[4];
#pragma unroll
    for (int tm = 0; tm < 4; ++tm)
        ba1v[tm] = *(const f32x4*)(ba1 + tm * 16 + q4 * 4);
    f32x4 acc[4][2];
#pragma unroll
    for (int tm = 0; tm < 4; ++tm)
#pragma unroll
        for (int tn = 0; tn < 2; ++tn) acc[tm][tn] = ba1v[tm];
#pragma unroll
    for (int ks = 0; ks < 2; ++ks) {
        short8 aw[4];
#pragma unroll
        for (int tm = 0; tm < 4; ++tm)
            aw[tm] = ldfrag(lds, O_WA1, tm * 16 + lid, ks * 64 + kb);
#pragma unroll
        for (int tn = 0; tn < 2; ++tn) {
            short8 bt = ldfrag(lds, O_TH, (jt0 + tn) * 16 + lid, ks * 64 + kb);
#pragma unroll
            for (int tm = 0; tm < 4; ++tm)
                acc[tm][tn] = __builtin_amdgcn_mfma_f32_16x16x32_bf16(aw[tm], bt, acc[tm][tn], 0, 0, 0);
        }
    }
#pragma unroll
    for (int tm = 0; tm < 4; ++tm)
#pragma unroll
        for (int tn = 0; tn < 2; ++tn) {
            int j = (jt0 + tn) * 16 + lid;
            uint2 w;
            w.x = cvtpk(fmaxf(acc[tm][tn][0], 0.f), fmaxf(acc[tm][tn][1], 0.f));
            w.y = cvtpk(fmaxf(acc[tm][tn][2], 0.f), fmaxf(acc[tm][tn][3], 0.f));
            *(uint2*)(lds + O_TH + swb(j, tm * 32 + q4 * 8)) = w;
        }

    // ---- GEMM4: sim = Wa2^T @ h2^T (ba2 cancels in softmax)
#pragma unroll
    for (int tm = 0; tm < 4; ++tm)
#pragma unroll
        for (int tn = 0; tn < 2; ++tn) acc[tm][tn] = z4;
#pragma unroll
    for (int ks = 0; ks < 2; ++ks) {
        short8 aw[4];
#pragma unroll
        for (int tm = 0; tm < 4; ++tm)
            aw[tm] = ldfrag(lds, O_WA2, tm * 16 + lid, ks * 64 + kb);
#pragma unroll
        for (int tn = 0; tn < 2; ++tn) {
            short8 bt = ldfrag(lds, O_TH, (jt0 + tn) * 16 + lid, ks * 64 + kb);
#pragma unroll
            for (int tm = 0; tm < 4; ++tm)
                acc[tm][tn] = __builtin_amdgcn_mfma_f32_16x16x32_bf16(aw[tm], bt, acc[tm][tn], 0, 0, 0);
        }
    }

    // ---- softmax partial sums over this wave's 32 j
#pragma unroll
    for (int tm = 0; tm < 4; ++tm) {
        f32x4 num = z4, den = z4;
#pragma unroll
        for (int tn = 0; tn < 2; ++tn) {
            float vf0 = bf_lo(vvp[tm][tn].x), vf1 = bf_hi(vvp[tm][tn].x);
            float vf2 = bf_lo(vvp[tm][tn].y), vf3 = bf_hi(vvp[tm][tn].y);
            float e0 = __expf(acc[tm][tn][0]);
            float e1 = __expf(acc[tm][tn][1]);
            float e2 = __expf(acc[tm][tn][2]);
            float e3 = __expf(acc[tm][tn][3]);
            den[0] += e0; num[0] = fmaf(e0, vf0, num[0]);
            den[1] += e1; num[1] = fmaf(e1, vf1, num[1]);
            den[2] += e2; num[2] = fmaf(e2, vf2, num[2]);
            den[3] += e3; num[3] = fmaf(e3, vf3, num[3]);
        }
#pragma unroll
        for (int ofs = 1; ofs < 16; ofs <<= 1) {
#pragma unroll
            for (int g = 0; g < 4; ++g) {
                num[g] += __shfl_xor(num[g], ofs);
                den[g] += __shfl_xor(den[g], ofs);
            }
        }
        if (lid == 0) {
            int base = O_RED + ((wv * 4 + tm) * 4 + q4) * 32;
            *(f32x4*)(lds + base) = num;
            *(f32x4*)(lds + base + 16) = den;
        }
    }
    __syncthreads();

    if (tid < 64) {
        int tm = tid >> 4, qq = (tid >> 2) & 3, g = tid & 3;
        float nn = 0.f, dd = 0.f;
#pragma unroll
        for (int w = 0; w < 4; ++w) {
            int base = O_RED + ((w * 4 + tm) * 4 + qq) * 32 + g * 4;
            nn += *(const float*)(lds + base);
            dd += *(const float*)(lds + base + 16);
        }
        float* pb = part + (size_t)blk * 128;
        pb[tid] = nn;
        pb[64 + tid] = dd;
    }
}

// ---------------- Kernel C: out = relu(BN((num/den)@W2+b2) + skip), half-combine fused ----
__global__ __launch_bounds__(256) void fc2_kernel(
    const float* __restrict__ part, const float* __restrict__ W2, const float* __restrict__ b2,
    const float* __restrict__ g2, const float* __restrict__ bb2,
    const float* __restrict__ m2, const float* __restrict__ v2,
    const float* __restrict__ skip, float* __restrict__ out)
{
    const int ROWS = 8;
    __shared__ float ar[ROWS][INNER];
    const int n0 = blockIdx.x * ROWS;
    const int t = threadIdx.x;

    for (int idx = t; idx < ROWS * INNER; idx += 256) {
        int rr = idx >> 6, k = idx & 63;
        const float* pp = part + (size_t)(n0 + rr) * 256 + k;
        float nn = pp[0] + pp[128];
        float dd = pp[64] + pp[192];
        ar[rr][k] = nn / dd;
    }
    __syncthreads();

    const float s2 = g2[t] * rsqrtf(v2[t] + EPSV);
    const float base = b2[t] - m2[t];
    const float bet = bb2[t];

    float accv[ROWS];
#pragma unroll
    for (int rr = 0; rr < ROWS; ++rr) accv[rr] = 0.f;
    for (int k = 0; k < INNER; ++k) {
        float wv = W2[(size_t)k * CC + t];
#pragma unroll
        for (int rr = 0; rr < ROWS; ++rr) accv[rr] = fmaf(ar[rr][k], wv, accv[rr]);
    }
#pragma unroll
    for (int rr = 0; rr < ROWS; ++rr) {
        float y = (accv[rr] + base) * s2 + bet;
        out[(size_t)(n0 + rr) * CC + t] =
            fmaxf(y + skip[(size_t)(n0 + rr) * CC + t], 0.f);
    }
}

extern "C" void kernel_launch(void* const* d_in, const int* in_sizes, int n_in,
                              void* d_out, int out_size, void* d_ws, size_t ws_size,
                              hipStream_t stream)
{
    const float* x   = (const float*)d_in[0];
    const float* r   = (const float*)d_in[1];
    const float* W1  = (const float*)d_in[2];
    const float* b1  = (const float*)d_in[3];
    const float* g1  = (const float*)d_in[4];
    const float* bb1 = (const float*)d_in[5];
    const float* m1  = (const float*)d_in[6];
    const float* v1  = (const float*)d_in[7];
    const float* Wqkv= (const float*)d_in[8];
    const float* Wt1 = (const float*)d_in[9];
    const float* bt1 = (const float*)d_in[10];
    const float* gt  = (const float*)d_in[11];
    const float* bbt = (const float*)d_in[12];
    const float* mt  = (const float*)d_in[13];
    const float* vt  = (const float*)d_in[14];
    const float* Wt2 = (const float*)d_in[15];
    const float* bt2 = (const float*)d_in[16];
    const float* Wa1 = (const float*)d_in[17];
    const float* ba1 = (const float*)d_in[18];
    const float* Wa2 = (const float*)d_in[19];
    const float* W2  = (const float*)d_in[21];
    const float* b2  = (const float*)d_in[22];
    const float* g2  = (const float*)d_in[23];
    const float* bb2 = (const float*)d_in[24];
    const float* m2  = (const float*)d_in[25];
    const float* v2  = (const float*)d_in[26];
    float* out = (float*)d_out;

    const int N = BB * TT;                 // 4096 rows
    float* skip = (float*)d_ws;            // N*256 floats = 4 MB
    float* qkv  = skip + (size_t)N * CC;   // N*192 floats = 3 MB
    float* part = qkv  + (size_t)N * 192;  // 8192*128 floats = 4 MB (num|den per half)
    char*  img  = (char*)(part + (size_t)N * 2 * 128);  // 22.7KB weight image

    prep_kernel<<<dim3(4), dim3(256), 0, stream>>>(
        Wt1, bt1, gt, bbt, mt, vt, Wt2, Wa1, Wa2, img);
    fc1_qkv_kernel<<<dim3(N / 8), dim3(256), 0, stream>>>(
        x, W1, b1, g1, bb1, m1, v1, Wqkv, skip, qkv);
    attn_mfma_kernel<<<dim3(N * 2), dim3(256), 0, stream>>>(
        r, qkv, bt2, ba1, img, part);
    fc2_kernel<<<dim3(N / 8), dim3(256), 0, stream>>>(
        part, W2, b2, g2, bb2, m2, v2, skip, out);
}